// Round 2
// baseline (1948.488 us; speedup 1.0000x reference)
//
#include <hip/hip_runtime.h>

#define NN   8192
#define DD   128
#define KK   8
#define KM1  7
#define ROWS 4
#define CB   8          // columns per thread per pass
#define TPB  256

#define O0_END   57344
#define O1_END   7397376
#define O2_END   14737408
#define O3_END   22077440
#define TOTAL    23126016

__device__ __forceinline__ unsigned mix32(unsigned h) {
  h ^= h >> 16; h *= 0x85ebca6bu; h ^= h >> 13; h *= 0xc2b2ae35u; h ^= h >> 16;
  return h;
}

// One block handles ROWS consecutive anchor rows. Categorical sampling of
// KM1 negatives per row via the exponential race: argmin_j E_j / w_j with
// E ~ Exp(1), identical in distribution to Gumbel-argmax on log w.
// 1/w = (2*d2m)^63 * om^62 * sqrt(om)  (pure multiplies, range-safe),
// key = log2(u) * (-ln2 * 1/w)  -> one v_log_f32 per draw.
__global__ __launch_bounds__(TPB) void sample_negatives(const float* __restrict__ x,
                                                        int* __restrict__ nidx) {
  __shared__ float xa[ROWS][DD];
  __shared__ float red_s[ROWS][KM1][TPB / 64];
  __shared__ int   red_i[ROWS][KM1][TPB / 64];

  const int tid = threadIdx.x;
  const int i0  = blockIdx.x * ROWS;

  for (int t = tid; t < ROWS * DD; t += TPB) xa[t >> 7][t & 127] = x[i0 * DD + t];
  __syncthreads();

  float best[ROWS][KM1];
  int   bidx[ROWS][KM1];
#pragma unroll
  for (int r = 0; r < ROWS; ++r)
#pragma unroll
    for (int s = 0; s < KM1; ++s) { best[r][s] = 1e30f; bidx[r][s] = 0; }

  const int myblk = i0 >> 3;  // ROWS=4 rows never straddle a k=8 block
  const float4* xa4 = reinterpret_cast<const float4*>(&xa[0][0]);

  for (int base = 0; base < NN; base += TPB * CB) {
    float dot[CB][ROWS];
#pragma unroll
    for (int c = 0; c < CB; ++c)
#pragma unroll
      for (int r = 0; r < ROWS; ++r) dot[c][r] = 0.f;

#pragma unroll 2
    for (int d4 = 0; d4 < DD / 4; ++d4) {
      float4 a0 = xa4[0 * 32 + d4];   // broadcast LDS reads, hoisted out of c-loop
      float4 a1 = xa4[1 * 32 + d4];
      float4 a2 = xa4[2 * 32 + d4];
      float4 a3 = xa4[3 * 32 + d4];
#pragma unroll
      for (int c = 0; c < CB; ++c) {
        const int col = base + c * TPB + tid;
        float4 v = *reinterpret_cast<const float4*>(x + (size_t)col * DD + d4 * 4);
        dot[c][0] += v.x * a0.x + v.y * a0.y + v.z * a0.z + v.w * a0.w;
        dot[c][1] += v.x * a1.x + v.y * a1.y + v.z * a1.z + v.w * a1.w;
        dot[c][2] += v.x * a2.x + v.y * a2.y + v.z * a2.z + v.w * a2.w;
        dot[c][3] += v.x * a3.x + v.y * a3.y + v.z * a3.z + v.w * a3.w;
      }
    }

#pragma unroll
    for (int c = 0; c < CB; ++c) {
      const int col = base + c * TPB + tid;
      const bool vb = (col >> 3) != myblk;
#pragma unroll
      for (int r = 0; r < ROWS; ++r) {
        float d2m = fmaxf(2.0f - 2.0f * dot[c][r], 0.25f);
        if (vb && d2m < 1.96f) {
          float t  = d2m + d2m;                     // scale keeps range normal
          float t2 = t * t, t4 = t2 * t2, t8 = t4 * t4, t16 = t8 * t8, t32 = t16 * t16;
          float t63 = t32 * t16 * t8 * t4 * t2 * t; // (2*d2m)^63 <= 2.2e37
          float om  = fmaf(d2m, -0.25f, 1.0f);      // in (0.51, 0.9375]
          float o2 = om * om, o4 = o2 * o2, o8 = o4 * o4, o16 = o8 * o8, o32 = o16 * o16;
          float o62 = o32 * o16 * o8 * o4 * o2;
          float kscale = t63 * o62 * __fsqrt_rn(om) * (-0.69314718f);  // -ln2 / w
          unsigned h = mix32((unsigned)((i0 + r) * NN + col) + 0x9E3779B9u);
#pragma unroll
          for (int sm = 0; sm < KM1; ++sm) {
            h = h * 1664525u + 1013904223u;
            float u = (float)(h >> 9) * (1.0f / 8388608.0f) + (1.0f / 16777216.0f);
            float key = __log2f(u) * kscale;        // = E / w  (E = -ln u)
            if (key < best[r][sm]) { best[r][sm] = key; bidx[r][sm] = col; }
          }
        }
      }
    }
  }

  const int lane = tid & 63;
  const int wv   = tid >> 6;
#pragma unroll
  for (int r = 0; r < ROWS; ++r) {
#pragma unroll
    for (int sm = 0; sm < KM1; ++sm) {
      float sc = best[r][sm];
      int   ix = bidx[r][sm];
#pragma unroll
      for (int off = 32; off > 0; off >>= 1) {
        float os = __shfl_down(sc, off);
        int   oi = __shfl_down(ix, off);
        if (os < sc) { sc = os; ix = oi; }
      }
      if (lane == 0) { red_s[r][sm][wv] = sc; red_i[r][sm][wv] = ix; }
    }
  }
  __syncthreads();

  if (tid < ROWS * KM1) {
    int r = tid / KM1, sm = tid % KM1;
    float sc = red_s[r][sm][0];
    int   ix = red_i[r][sm][0];
    for (int w = 1; w < TPB / 64; ++w) {
      if (red_s[r][sm][w] < sc) { sc = red_s[r][sm][w]; ix = red_i[r][sm][w]; }
    }
    const int i = i0 + r;
    if (sc > 1e29f) {  // degenerate row -> uniform fallback (probs = 1/n)
      ix = (int)(mix32((unsigned)(i * KM1 + sm) * 0x68bc21ebu + 77u) & (NN - 1));
    }
    nidx[i * KM1 + sm] = ix;
  }
}

// All five output chunks, float4-vectorized (all boundaries are x128-aligned).
__global__ __launch_bounds__(256) void write_outputs(const float* __restrict__ x,
                                                     const int* __restrict__ nidx,
                                                     float4* __restrict__ out4) {
  const int q = blockIdx.x * 256 + threadIdx.x;
  if (q >= TOTAL / 4) return;
  const int e = q * 4;
  float4 v;
  if (e < O0_END) {
    v.x = (float)((e    ) / KM1);
    v.y = (float)((e + 1) / KM1);
    v.z = (float)((e + 2) / KM1);
    v.w = (float)((e + 3) / KM1);                       // a_idx
  } else if (e < O1_END) {
    int t = e - O0_END; int sidx = t >> 7; int d = t & 127;
    v = *reinterpret_cast<const float4*>(x + (sidx / KM1) * DD + d);   // x[a_idx]
  } else if (e < O2_END) {
    int t = e - O1_END; int sidx = t >> 7; int d = t & 127;
    int i = sidx / KM1; int j = sidx - i * KM1; int m = i & (KK - 1);
    int p = (i >> 3) * KK + j + (j >= m ? 1 : 0);       // block members, skip self
    v = *reinterpret_cast<const float4*>(x + p * DD + d);              // x[p_idx]
  } else if (e < O3_END) {
    int t = e - O2_END; int sidx = t >> 7; int d = t & 127;
    v = *reinterpret_cast<const float4*>(x + nidx[sidx] * DD + d);     // x[n_idx]
  } else {
    v = *reinterpret_cast<const float4*>(x + (e - O3_END));            // x
  }
  out4[q] = v;
}

extern "C" void kernel_launch(void* const* d_in, const int* in_sizes, int n_in,
                              void* d_out, int out_size, void* d_ws, size_t ws_size,
                              hipStream_t stream) {
  const float* x = (const float*)d_in[0];
  float* out = (float*)d_out;
  int* nidx = (int*)d_ws;  // 57344 ints of scratch

  hipLaunchKernelGGL(sample_negatives, dim3(NN / ROWS), dim3(TPB), 0, stream, x, nidx);
  hipLaunchKernelGGL(write_outputs, dim3((TOTAL / 4 + 255) / 256), dim3(256), 0, stream,
                     x, nidx, (float4*)out);
}

// Round 3
// 591.663 us; speedup vs baseline: 3.2932x; 3.2932x over previous
//
#include <hip/hip_runtime.h>
#include <math.h>

#define NN   8192
#define DD   128
#define KM1  7
#define AB   128      // anchors per block
#define CQ   2048     // columns per block (one quarter of N)
#define NB   64       // columns per LDS tile
#define CW   68       // colT row stride in floats (pad 4, keeps 16B alignment)
#define TPB  256

#define O0_END   57344
#define O1_END   7397376
#define O2_END   14737408
#define O3_END   22077440
#define TOTAL    23126016
#define NKEY     (NN * KM1)   // 57344

__device__ __forceinline__ unsigned mix32(unsigned h) {
  h ^= h >> 16; h *= 0x85ebca6bu; h ^= h >> 13; h *= 0xc2b2ae35u; h ^= h >> 16;
  return h;
}

// Block = 128 anchors x 2048 cols. grid = 64 anchor-groups x 4 col-quarters = 256.
// Exponential-race categorical sampling: argmin_j E_j/w_j over this block's cols.
// 1/w = (2*d2m)^63 * om^62.5 (repeated squaring; range [1.9e-21, 1.2e19], normal).
// key = (log2(h) - 32)*(-ln2/w) computed as fma(log2(h), ks, bias).
__global__ __launch_bounds__(TPB, 1) void sample_partial(const float* __restrict__ x,
                                                         float* __restrict__ keys,
                                                         int* __restrict__ idxs) {
  __shared__ float aT[128 * 128];   // aT[d][a], 64 KB, broadcast reads
  __shared__ float colT[128 * CW];  // colT[d][c], 34.8 KB

  const int tid = threadIdx.x;
  const int q   = blockIdx.x & 3;
  const int i0  = (blockIdx.x >> 2) * AB;
  const int c0  = q * CQ;

  // ---- stage transposed anchors (once): coalesced reads (lane = consecutive d)
  {
    const int d = tid & 127, half = tid >> 7;
    for (int j = 0; j < 64; ++j) {
      const int a = half * 64 + j;
      aT[d * 128 + a] = x[(size_t)(i0 + a) * DD + d];
    }
  }

  float best[8][KM1];
  int   bidx[8][KM1];
#pragma unroll
  for (int a = 0; a < 8; ++a)
#pragma unroll
    for (int s = 0; s < KM1; ++s) { best[a][s] = 1e30f; bidx[a][s] = 0; }

  const int c4  = (tid & 15) * 4;   // this thread's 4 cols within tile
  const int a8  = (tid >> 4) * 8;   // this thread's 8 anchors

  for (int tile = 0; tile < CQ / NB; ++tile) {
    const int ct = c0 + tile * NB;
    // ---- stage colT: coalesced global (256B/instr), 8-way LDS write conflicts (cheap)
    {
      const int d = tid & 127, half = tid >> 7;
#pragma unroll
      for (int j = 0; j < 32; ++j) {
        const int c = half * 32 + j;
        colT[d * CW + c] = x[(size_t)(ct + c) * DD + d];
      }
    }
    __syncthreads();

    float acc[8][4];
#pragma unroll
    for (int a = 0; a < 8; ++a)
#pragma unroll
      for (int c = 0; c < 4; ++c) acc[a][c] = 0.f;

#pragma unroll 8
    for (int d = 0; d < 128; ++d) {
      float4 af0 = *reinterpret_cast<const float4*>(aT + d * 128 + a8);
      float4 af1 = *reinterpret_cast<const float4*>(aT + d * 128 + a8 + 4);
      float4 cf  = *reinterpret_cast<const float4*>(colT + d * CW + c4);
      float af[8] = {af0.x, af0.y, af0.z, af0.w, af1.x, af1.y, af1.z, af1.w};
#pragma unroll
      for (int a = 0; a < 8; ++a) {
        acc[a][0] = fmaf(af[a], cf.x, acc[a][0]);
        acc[a][1] = fmaf(af[a], cf.y, acc[a][1]);
        acc[a][2] = fmaf(af[a], cf.z, acc[a][2]);
        acc[a][3] = fmaf(af[a], cf.w, acc[a][3]);
      }
    }
    __syncthreads();

    // ---- epilogue: weights + 7 exponential-race draws per pair (branchless)
#pragma unroll
    for (int a = 0; a < 8; ++a) {
      const int row = i0 + a8 + a;
#pragma unroll
      for (int c = 0; c < 4; ++c) {
        const int colg = ct + c4 + c;
        float d2m = fmaxf(fmaf(-2.0f, acc[a][c], 2.0f), 0.25f);
        const bool vb = ((row >> 3) != (colg >> 3)) && (d2m < 1.96f);
        float t  = d2m + d2m;
        float t2 = t * t, t4 = t2 * t2, t8 = t4 * t4, t16 = t8 * t8, t32 = t16 * t16;
        float t63 = t32 * t16 * t8 * t4 * t2 * t;       // (2*d2m)^63
        float om  = fmaf(d2m, -0.25f, 1.0f);            // (0.51, 0.9375]
        float o2 = om * om, o4 = o2 * o2, o8 = o4 * o4, o16 = o8 * o8, o32 = o16 * o16;
        float o62 = o32 * o16 * o8 * o4 * o2;
        float inw = t63 * o62 * __fsqrt_rn(om);         // 1/w (scaled)
        float ks   = vb ? inw * (-0.69314718f) : 0.0f;  // -ln2/w
        float bias = vb ? inw * 22.1807098f : INFINITY; // +32*ln2/w
        unsigned h = mix32((unsigned)(row * NN + colg) + 0x9E3779B9u);
#pragma unroll
        for (int sm = 0; sm < KM1; ++sm) {
          h = h * 1664525u + 1013904223u;
          float lg  = __log2f((float)h);                // h=0 -> -inf -> key NaN/inf: skipped
          float key = fmaf(lg, ks, bias);               // E/w, valid keys in [0, 2.7e20]
          if (key < best[a][sm]) { best[a][sm] = key; bidx[a][sm] = colg; }
        }
      }
    }
  }

  // ---- reduce across the 16 lanes sharing an anchor-group (same a8)
#pragma unroll
  for (int a = 0; a < 8; ++a)
#pragma unroll
    for (int s = 0; s < KM1; ++s) {
      float k = best[a][s];
      int   ix = bidx[a][s];
#pragma unroll
      for (int off = 8; off > 0; off >>= 1) {
        float k2 = __shfl_xor(k, off);
        int   x2 = __shfl_xor(ix, off);
        if (k2 < k || (k2 == k && x2 < ix)) { k = k2; ix = x2; }
      }
      best[a][s] = k; bidx[a][s] = ix;
    }

  if ((tid & 15) == 0) {
#pragma unroll
    for (int a = 0; a < 8; ++a) {
      const int row = i0 + a8 + a;
#pragma unroll
      for (int s = 0; s < KM1; ++s) {
        keys[(size_t)q * NKEY + row * KM1 + s] = best[a][s];
        idxs[(size_t)q * NKEY + row * KM1 + s] = bidx[a][s];
      }
    }
  }
}

// Pick the min-key candidate across the 4 column-quarters; uniform fallback.
__global__ __launch_bounds__(256) void combine(const float* __restrict__ keys,
                                               const int* __restrict__ idxs,
                                               int* __restrict__ nidx) {
  const int idx = blockIdx.x * 256 + threadIdx.x;
  if (idx >= NKEY) return;
  float bk = 1e30f;
  int   bi = 0;
#pragma unroll
  for (int q = 0; q < 4; ++q) {
    float k = keys[(size_t)q * NKEY + idx];
    int   ix = idxs[(size_t)q * NKEY + idx];
    if (k < bk || (k == bk && k < 9.9e29f && ix < bi)) { bk = k; bi = ix; }
  }
  if (bk >= 9.9e29f) {  // no valid pair anywhere -> uniform fallback (probs = 1/n)
    bi = (int)(mix32((unsigned)idx * 0x68bc21ebu + 77u) & (NN - 1));
  }
  nidx[idx] = bi;
}

// All five output chunks, float4-vectorized (all boundaries are x128-aligned).
__global__ __launch_bounds__(256) void write_outputs(const float* __restrict__ x,
                                                     const int* __restrict__ nidx,
                                                     float4* __restrict__ out4) {
  const int qq = blockIdx.x * 256 + threadIdx.x;
  if (qq >= TOTAL / 4) return;
  const int e = qq * 4;
  float4 v;
  if (e < O0_END) {
    v.x = (float)((e    ) / KM1);
    v.y = (float)((e + 1) / KM1);
    v.z = (float)((e + 2) / KM1);
    v.w = (float)((e + 3) / KM1);                       // a_idx
  } else if (e < O1_END) {
    int t = e - O0_END; int sidx = t >> 7; int d = t & 127;
    v = *reinterpret_cast<const float4*>(x + (size_t)(sidx / KM1) * DD + d);  // x[a_idx]
  } else if (e < O2_END) {
    int t = e - O1_END; int sidx = t >> 7; int d = t & 127;
    int i = sidx / KM1; int j = sidx - i * KM1; int m = i & 7;
    int p = (i >> 3) * 8 + j + (j >= m ? 1 : 0);        // block members, skip self
    v = *reinterpret_cast<const float4*>(x + (size_t)p * DD + d);             // x[p_idx]
  } else if (e < O3_END) {
    int t = e - O2_END; int sidx = t >> 7; int d = t & 127;
    v = *reinterpret_cast<const float4*>(x + (size_t)nidx[sidx] * DD + d);    // x[n_idx]
  } else {
    v = *reinterpret_cast<const float4*>(x + (e - O3_END));                   // x
  }
  out4[qq] = v;
}

extern "C" void kernel_launch(void* const* d_in, const int* in_sizes, int n_in,
                              void* d_out, int out_size, void* d_ws, size_t ws_size,
                              hipStream_t stream) {
  const float* x = (const float*)d_in[0];
  float* out = (float*)d_out;

  float* keys = (float*)d_ws;                 // 4 * 57344 floats
  int*   idxs = (int*)d_ws + 4 * NKEY;        // 4 * 57344 ints
  int*   nidx = (int*)d_ws + 8 * NKEY;        // 57344 ints   (total ~2.06 MB)

  hipLaunchKernelGGL(sample_partial, dim3(256), dim3(TPB), 0, stream, x, keys, idxs);
  hipLaunchKernelGGL(combine, dim3((NKEY + 255) / 256), dim3(256), 0, stream,
                     keys, idxs, nidx);
  hipLaunchKernelGGL(write_outputs, dim3(TOTAL / 4 / 256), dim3(256), 0, stream,
                     x, nidx, (float4*)out);
}

// Round 5
// 529.067 us; speedup vs baseline: 3.6829x; 1.1183x over previous
//
#include <hip/hip_runtime.h>

#define NN   8192
#define DD   128
#define KM1  7
#define TPB  256

#define O0_END   57344
#define O1_END   7397376
#define O2_END   14737408
#define O3_END   22077440
#define TOTAL    23126016
#define NKEY     57344

typedef __attribute__((ext_vector_type(8))) short bf16x8;
typedef __attribute__((ext_vector_type(4))) float f32x4;

__device__ __forceinline__ unsigned mix32(unsigned h) {
  h ^= h >> 16; h *= 0x85ebca6bu; h ^= h >> 13; h *= 0xc2b2ae35u; h ^= h >> 16;
  return h;
}

// fp32 -> bf16 (RNE), 4 elems/thread
__global__ __launch_bounds__(256) void to_bf16(const float4* __restrict__ x4,
                                               ushort4* __restrict__ xb4) {
  const int i = blockIdx.x * 256 + threadIdx.x;  // 262144 float4's
  float4 v = x4[i];
  ushort4 o;
  unsigned u;
  u = __float_as_uint(v.x); o.x = (unsigned short)((u + 0x7FFFu + ((u >> 16) & 1u)) >> 16);
  u = __float_as_uint(v.y); o.y = (unsigned short)((u + 0x7FFFu + ((u >> 16) & 1u)) >> 16);
  u = __float_as_uint(v.z); o.z = (unsigned short)((u + 0x7FFFu + ((u >> 16) & 1u)) >> 16);
  u = __float_as_uint(v.w); o.w = (unsigned short)((u + 0x7FFFu + ((u >> 16) & 1u)) >> 16);
  xb4[i] = o;
}

// Grid 64x64 tiles of 128x128 pairs. 4 waves/block, each owns a 64x64 tile.
// sim via bf16 MFMA (direct-global fragments); exponential-race sampling with
// col packed into the key's low 13 bits; winner via u32 atomicMin.
__global__ __launch_bounds__(TPB, 3) void sample_mfma(const unsigned short* __restrict__ xb,
                                                      unsigned* __restrict__ nidxp) {
  const int tid  = threadIdx.x;
  const int lane = tid & 63;
  const int wid  = tid >> 6;
  const int l15  = lane & 15;
  const int g    = lane >> 4;
  const int i0   = ((int)(blockIdx.x >> 6)) * 128 + (wid >> 1) * 64;
  const int c0   = ((int)(blockIdx.x & 63)) * 128 + (wid & 1) * 64;
  const int koff = g * 8;

  // preload B fragments (cols): B[k][n] = xb[col n][k]
  bf16x8 b[4][4];
#pragma unroll
  for (int nf = 0; nf < 4; ++nf) {
    const unsigned short* bp = xb + (size_t)(c0 + nf * 16 + l15) * DD + koff;
#pragma unroll
    for (int kk = 0; kk < 4; ++kk)
      b[nf][kk] = *reinterpret_cast<const bf16x8*>(bp + kk * 32);
  }

  f32x4 acc[4][4];
#pragma unroll
  for (int mf = 0; mf < 4; ++mf)
#pragma unroll
    for (int nf = 0; nf < 4; ++nf) acc[mf][nf] = (f32x4){0.f, 0.f, 0.f, 0.f};

#pragma unroll
  for (int mf = 0; mf < 4; ++mf) {
    bf16x8 a[4];
    const unsigned short* ap = xb + (size_t)(i0 + mf * 16 + l15) * DD + koff;
#pragma unroll
    for (int kk = 0; kk < 4; ++kk)
      a[kk] = *reinterpret_cast<const bf16x8*>(ap + kk * 32);
#pragma unroll
    for (int nf = 0; nf < 4; ++nf)
#pragma unroll
      for (int kk = 0; kk < 4; ++kk)
        acc[mf][nf] = __builtin_amdgcn_mfma_f32_16x16x32_bf16(a[kk], b[nf][kk],
                                                              acc[mf][nf], 0, 0, 0);
  }

  // epilogue: C/D layout col = lane&15, row = (lane>>4)*4 + reg  [m89-verified]
#pragma unroll
  for (int mf = 0; mf < 4; ++mf) {
    const int rowbase = i0 + mf * 16 + g * 4;   // 4 consecutive rows, same 8-block
    const int rowblk  = rowbase >> 3;
    unsigned best[4][KM1];
#pragma unroll
    for (int r = 0; r < 4; ++r)
#pragma unroll
      for (int s = 0; s < KM1; ++s) best[r][s] = 0xFFFFFFFFu;

#pragma unroll
    for (int nf = 0; nf < 4; ++nf) {
      const int col  = c0 + nf * 16 + l15;
      const bool nblk = ((col >> 3) != rowblk);
#pragma unroll
      for (int r = 0; r < 4; ++r) {
        const int row = rowbase + r;
        float dot = acc[mf][nf][r];
        float d2m = fmaxf(fmaf(-2.f, dot, 2.f), 0.25f);   // clamped dist^2
        bool vb  = nblk && (d2m < 1.96f);                 // mask: block + dist<1.4
        float lgd = __log2f(d2m);
        float om  = fmaf(-0.25f, d2m, 1.f);
        float lgo = __log2f(om);
        float lgs = fmaf(63.f, lgd, 63.f) + 62.5f * lgo;  // log2((2*d2m)^63 * om^62.5)
        float inw = __builtin_amdgcn_exp2f(lgs);          // 1/w, in [2^-124, 2^118]
        float ks   = vb ? inw * (-0.69314718f) : 0.f;
        float bias = vb ? inw * 22.180710f : __builtin_inff();
        unsigned h = mix32((unsigned)((row << 13) | col) + 0x9E3779B9u);
#pragma unroll
        for (int sm = 0; sm < KM1; ++sm) {
          h = h * 1664525u + 1013904223u;
          float lg  = __log2f((float)(h | 1u));           // in [0,32)
          float key = fmaf(lg, ks, bias);                 // E/w >= 0 (inf if masked)
          unsigned pk = (__float_as_uint(key) & 0xFFFFE000u) | (unsigned)col;
          best[r][sm] = best[r][sm] < pk ? best[r][sm] : pk;
        }
      }
    }
    // reduce across the 16 lanes sharing these rows (xor 1,2,4,8 stays in-group)
#pragma unroll
    for (int r = 0; r < 4; ++r)
#pragma unroll
      for (int s = 0; s < KM1; ++s) {
        unsigned v = best[r][s];
#pragma unroll
        for (int off = 1; off < 16; off <<= 1) {
          unsigned o = (unsigned)__shfl_xor((int)v, off);
          v = v < o ? v : o;
        }
        best[r][s] = v;
      }
    if (l15 == 0) {
#pragma unroll
      for (int r = 0; r < 4; ++r)
#pragma unroll
        for (int s = 0; s < KM1; ++s)
          atomicMin(&nidxp[(rowbase + r) * KM1 + s], best[r][s]);
    }
  }
}

// All five output chunks, float4-vectorized; O3 decodes the packed winner inline.
__global__ __launch_bounds__(256) void write_outputs(const float* __restrict__ x,
                                                     const unsigned* __restrict__ nidxp,
                                                     float4* __restrict__ out4) {
  const int qq = blockIdx.x * 256 + threadIdx.x;
  if (qq >= TOTAL / 4) return;
  const int e = qq * 4;
  float4 v;
  if (e < O0_END) {
    v.x = (float)((e    ) / KM1);
    v.y = (float)((e + 1) / KM1);
    v.z = (float)((e + 2) / KM1);
    v.w = (float)((e + 3) / KM1);                        // a_idx
  } else if (e < O1_END) {
    int t = e - O0_END; int sidx = t >> 7; int d = t & 127;
    v = *reinterpret_cast<const float4*>(x + (size_t)(sidx / KM1) * DD + d);   // x[a_idx]
  } else if (e < O2_END) {
    int t = e - O1_END; int sidx = t >> 7; int d = t & 127;
    int i = sidx / KM1; int j = sidx - i * KM1; int m = i & 7;
    int p = (i >> 3) * 8 + j + (j >= m ? 1 : 0);         // block members, skip self
    v = *reinterpret_cast<const float4*>(x + (size_t)p * DD + d);              // x[p_idx]
  } else if (e < O3_END) {
    int t = e - O2_END; int sidx = t >> 7; int d = t & 127;
    unsigned pk = nidxp[sidx];
    int nix = (pk >= 0x7F800000u)
                  ? (int)(mix32((unsigned)sidx * 0x68bc21ebu + 77u) & (NN - 1))
                  : (int)(pk & 0x1FFFu);                 // uniform fallback / winner col
    v = *reinterpret_cast<const float4*>(x + (size_t)nix * DD + d);            // x[n_idx]
  } else {
    v = *reinterpret_cast<const float4*>(x + (e - O3_END));                    // x
  }
  out4[qq] = v;
}

extern "C" void kernel_launch(void* const* d_in, const int* in_sizes, int n_in,
                              void* d_out, int out_size, void* d_ws, size_t ws_size,
                              hipStream_t stream) {
  const float* x = (const float*)d_in[0];
  float* out = (float*)d_out;

  unsigned* nidxp = (unsigned*)d_ws;                               // 57344 u32
  unsigned short* xb = (unsigned short*)((char*)d_ws + NKEY * 4);  // 8192x128 bf16 (2 MB)

  (void)hipMemsetAsync(nidxp, 0xFF, NKEY * 4, stream);
  hipLaunchKernelGGL(to_bf16, dim3(NN * DD / 4 / 256), dim3(256), 0, stream,
                     (const float4*)x, (ushort4*)xb);
  hipLaunchKernelGGL(sample_mfma, dim3(64 * 64), dim3(TPB), 0, stream, xb, nidxp);
  hipLaunchKernelGGL(write_outputs, dim3(TOTAL / 4 / 256), dim3(256), 0, stream,
                     x, nidxp, (float4*)out);
}

// Round 6
// 275.180 us; speedup vs baseline: 7.0808x; 1.9226x over previous
//
#include <hip/hip_runtime.h>

#define NN   8192
#define DD   128
#define KM1  7
#define QOC  4        // column quarters
#define TPB  256

#define O0_END   57344
#define O1_END   7397376
#define O2_END   14737408
#define O3_END   22077440
#define TOTAL    23126016
#define NKEY     57344

typedef __attribute__((ext_vector_type(8))) short bf16x8;
typedef __attribute__((ext_vector_type(4))) float f32x4;

__device__ __forceinline__ unsigned mix32(unsigned h) {
  h ^= h >> 16; h *= 0x85ebca6bu; h ^= h >> 13; h *= 0xc2b2ae35u; h ^= h >> 16;
  return h;
}

// fp32 -> bf16 (RNE), 4 elems/thread
__global__ __launch_bounds__(256) void to_bf16(const float4* __restrict__ x4,
                                               ushort4* __restrict__ xb4) {
  const int i = blockIdx.x * 256 + threadIdx.x;  // 262144 float4's
  float4 v = x4[i];
  ushort4 o;
  unsigned u;
  u = __float_as_uint(v.x); o.x = (unsigned short)((u + 0x7FFFu + ((u >> 16) & 1u)) >> 16);
  u = __float_as_uint(v.y); o.y = (unsigned short)((u + 0x7FFFu + ((u >> 16) & 1u)) >> 16);
  u = __float_as_uint(v.z); o.z = (unsigned short)((u + 0x7FFFu + ((u >> 16) & 1u)) >> 16);
  u = __float_as_uint(v.w); o.w = (unsigned short)((u + 0x7FFFu + ((u >> 16) & 1u)) >> 16);
  xb4[i] = o;
}

// Wave = 16 rows x 2048 cols (one quarter). 4 waves/block = 4 row-groups,
// same quarter (B fragments shared -> L1/L2 reuse). 512 blocks total.
// Exponential-race categorical sampling; per-lane running best (28 regs),
// ONE cross-lane reduce at the end, plain stores to partial[quarter] - no atomics.
__global__ __launch_bounds__(TPB, 2) void sample_mfma(const unsigned short* __restrict__ xb,
                                                      unsigned* __restrict__ partial) {
  const int tid  = threadIdx.x;
  const int lane = tid & 63;
  const int wid  = tid >> 6;
  const int l15  = lane & 15;
  const int g    = lane >> 4;
  const int i0   = (((int)(blockIdx.x >> 2)) * 4 + wid) * 16;  // wave's 16 rows
  const int oc   = (int)(blockIdx.x & 3);
  const int c0   = oc * 2048;
  const int koff = g * 8;

  // A fragments (this wave's 16 rows), loaded once
  bf16x8 a[4];
  {
    const unsigned short* ap = xb + (size_t)(i0 + l15) * DD + koff;
#pragma unroll
    for (int kk = 0; kk < 4; ++kk)
      a[kk] = *reinterpret_cast<const bf16x8*>(ap + kk * 32);
  }

  const int rowblk = (i0 + g * 4) >> 3;  // lane's 4 rows share one 8-block
  unsigned best[4][KM1];
#pragma unroll
  for (int r = 0; r < 4; ++r)
#pragma unroll
    for (int s = 0; s < KM1; ++s) best[r][s] = 0xFFFFFFFFu;

  auto loadB = [&](int t, bf16x8 b[4][4]) {
    const int ct = c0 + t * 64;
#pragma unroll
    for (int nf = 0; nf < 4; ++nf) {
      const unsigned short* bp = xb + (size_t)(ct + nf * 16 + l15) * DD + koff;
#pragma unroll
      for (int kk = 0; kk < 4; ++kk)
        b[nf][kk] = *reinterpret_cast<const bf16x8*>(bp + kk * 32);
    }
  };

  auto compute = [&](int t, bf16x8 b[4][4]) {
    const int ct = c0 + t * 64;
    f32x4 acc[4];
#pragma unroll
    for (int nf = 0; nf < 4; ++nf) acc[nf] = (f32x4){0.f, 0.f, 0.f, 0.f};
#pragma unroll
    for (int nf = 0; nf < 4; ++nf)
#pragma unroll
      for (int kk = 0; kk < 4; ++kk)
        acc[nf] = __builtin_amdgcn_mfma_f32_16x16x32_bf16(a[kk], b[nf][kk], acc[nf], 0, 0, 0);

    // epilogue: C/D layout col = l15, row = g*4 + reg  [m89-verified]
#pragma unroll
    for (int nf = 0; nf < 4; ++nf) {
      const int col  = ct + nf * 16 + l15;
      const bool nblk = ((col >> 3) != rowblk);
#pragma unroll
      for (int r = 0; r < 4; ++r) {
        const int row = i0 + g * 4 + r;
        float dot = acc[nf][r];
        float d2m = fmaxf(fmaf(-2.f, dot, 2.f), 0.25f);   // clamped dist^2
        bool vb  = nblk && (d2m < 1.96f);                 // block mask + dist<1.4
        float lgd = __log2f(d2m);
        float om  = fmaf(-0.25f, d2m, 1.f);
        float lgo = __log2f(om);
        float lgs = fmaf(63.f, lgd, 63.f) + 62.5f * lgo;  // log2((2*d2m)^63 * om^62.5)
        float inw = __builtin_amdgcn_exp2f(lgs);          // 1/w in [1.9e-21, 1.2e19]
        float ks   = vb ? inw * (-0.69314718f) : 0.f;
        float bias = vb ? inw * 22.180710f : __builtin_inff();
        unsigned h = mix32((unsigned)((row << 13) | col) + 0x9E3779B9u);
#pragma unroll
        for (int sm = 0; sm < KM1; ++sm) {
          h = h * 1664525u + 1013904223u;
          float lg  = __log2f((float)(h | 1u));           // [0,32)
          float key = fmaf(lg, ks, bias);                 // E/w >= 0 (inf if masked)
          unsigned pk = (__float_as_uint(key) & 0xFFFFE000u) | (unsigned)col;
          best[r][sm] = best[r][sm] < pk ? best[r][sm] : pk;
        }
      }
    }
  };

  // 32 col-tiles, register double-buffered B fragments
  bf16x8 b0[4][4], b1[4][4];
  loadB(0, b0);
  for (int t = 0; t < 32; t += 2) {
    loadB(t + 1, b1);
    compute(t, b0);
    if (t + 2 < 32) loadB(t + 2, b0);
    compute(t + 1, b1);
  }

  // one cross-lane reduce at the end (over l15 within the same g-group)
#pragma unroll
  for (int r = 0; r < 4; ++r)
#pragma unroll
    for (int s = 0; s < KM1; ++s) {
      unsigned v = best[r][s];
#pragma unroll
      for (int off = 1; off < 16; off <<= 1) {
        unsigned o = (unsigned)__shfl_xor((int)v, off);
        v = v < o ? v : o;
      }
      best[r][s] = v;
    }
  if (l15 == 0) {
#pragma unroll
    for (int r = 0; r < 4; ++r)
#pragma unroll
      for (int s = 0; s < KM1; ++s)
        partial[(size_t)oc * NKEY + (i0 + g * 4 + r) * KM1 + s] = best[r][s];
  }
}

// Min over the 4 quarters; decode winner col; uniform fallback. Writes the
// final index in place over the q=0 slice (each thread owns its slot).
__global__ __launch_bounds__(256) void combine(unsigned* __restrict__ partial) {
  const int idx = blockIdx.x * 256 + threadIdx.x;  // NKEY threads exactly
  unsigned bk = 0xFFFFFFFFu;
#pragma unroll
  for (int q = 0; q < QOC; ++q) {
    unsigned v = partial[(size_t)q * NKEY + idx];
    bk = bk < v ? bk : v;
  }
  unsigned col;
  if (bk >= 0x7F800000u) {  // all masked -> uniform fallback (probs = 1/n)
    col = mix32((unsigned)idx * 0x68bc21ebu + 77u) & (NN - 1);
  } else {
    col = bk & 0x1FFFu;
  }
  partial[idx] = col;
}

// All five output chunks, float4-vectorized.
__global__ __launch_bounds__(256) void write_outputs(const float* __restrict__ x,
                                                     const unsigned* __restrict__ nidx,
                                                     float4* __restrict__ out4) {
  const int qq = blockIdx.x * 256 + threadIdx.x;
  if (qq >= TOTAL / 4) return;
  const int e = qq * 4;
  float4 v;
  if (e < O0_END) {
    v.x = (float)((e    ) / KM1);
    v.y = (float)((e + 1) / KM1);
    v.z = (float)((e + 2) / KM1);
    v.w = (float)((e + 3) / KM1);                        // a_idx
  } else if (e < O1_END) {
    int t = e - O0_END; int sidx = t >> 7; int d = t & 127;
    v = *reinterpret_cast<const float4*>(x + (size_t)(sidx / KM1) * DD + d);   // x[a_idx]
  } else if (e < O2_END) {
    int t = e - O1_END; int sidx = t >> 7; int d = t & 127;
    int i = sidx / KM1; int j = sidx - i * KM1; int m = i & 7;
    int p = (i >> 3) * 8 + j + (j >= m ? 1 : 0);         // block members, skip self
    v = *reinterpret_cast<const float4*>(x + (size_t)p * DD + d);              // x[p_idx]
  } else if (e < O3_END) {
    int t = e - O2_END; int sidx = t >> 7; int d = t & 127;
    int nix = (int)nidx[sidx];
    v = *reinterpret_cast<const float4*>(x + (size_t)nix * DD + d);            // x[n_idx]
  } else {
    v = *reinterpret_cast<const float4*>(x + (e - O3_END));                    // x
  }
  out4[qq] = v;
}

extern "C" void kernel_launch(void* const* d_in, const int* in_sizes, int n_in,
                              void* d_out, int out_size, void* d_ws, size_t ws_size,
                              hipStream_t stream) {
  const float* x = (const float*)d_in[0];
  float* out = (float*)d_out;

  unsigned* partial = (unsigned*)d_ws;                                  // 4*57344 u32
  unsigned short* xb = (unsigned short*)((char*)d_ws + QOC * NKEY * 4); // 2 MB bf16

  hipLaunchKernelGGL(to_bf16, dim3(NN * DD / 4 / 256), dim3(256), 0, stream,
                     (const float4*)x, (ushort4*)xb);
  hipLaunchKernelGGL(sample_mfma, dim3(512), dim3(TPB), 0, stream, xb, partial);
  hipLaunchKernelGGL(combine, dim3(NKEY / 256), dim3(256), 0, stream, partial);
  hipLaunchKernelGGL(write_outputs, dim3(TOTAL / 4 / 256), dim3(256), 0, stream,
                     x, partial, (float4*)out);
}

// Round 7
// 215.782 us; speedup vs baseline: 9.0299x; 1.2753x over previous
//
#include <hip/hip_runtime.h>

#define NN   8192
#define DD   128
#define KM1  7
#define QOC  4        // column quarters
#define TPB  256

#define O0_END   57344
#define O1_END   7397376
#define O2_END   14737408
#define O3_END   22077440
#define TOTAL    23126016
#define NKEY     57344

typedef __attribute__((ext_vector_type(8))) short bf16x8;
typedef __attribute__((ext_vector_type(4))) float f32x4;

__device__ __forceinline__ unsigned mix32(unsigned h) {
  h ^= h >> 16; h *= 0x85ebca6bu; h ^= h >> 13; h *= 0xc2b2ae35u; h ^= h >> 16;
  return h;
}

// fp32 -> bf16 (RNE), 4 elems/thread
__global__ __launch_bounds__(256) void to_bf16(const float4* __restrict__ x4,
                                               ushort4* __restrict__ xb4) {
  const int i = blockIdx.x * 256 + threadIdx.x;  // 262144 float4's
  float4 v = x4[i];
  ushort4 o;
  unsigned u;
  u = __float_as_uint(v.x); o.x = (unsigned short)((u + 0x7FFFu + ((u >> 16) & 1u)) >> 16);
  u = __float_as_uint(v.y); o.y = (unsigned short)((u + 0x7FFFu + ((u >> 16) & 1u)) >> 16);
  u = __float_as_uint(v.z); o.z = (unsigned short)((u + 0x7FFFu + ((u >> 16) & 1u)) >> 16);
  u = __float_as_uint(v.w); o.w = (unsigned short)((u + 0x7FFFu + ((u >> 16) & 1u)) >> 16);
  xb4[i] = o;
}

// Wave = 16 rows x 2048 cols (one quarter), 64 tiles of 32 cols.
// Single statically-indexed B buffer (no lambdas/array-params -> no scratch).
// Exponential-race categorical sampling; per-lane running best (28 regs),
// one cross-lane reduce at the end, plain stores to partial[quarter].
__global__ __launch_bounds__(TPB, 2) void sample_mfma(const unsigned short* __restrict__ xb,
                                                      unsigned* __restrict__ partial) {
  const int tid  = threadIdx.x;
  const int lane = tid & 63;
  const int wid  = tid >> 6;
  const int l15  = lane & 15;
  const int g    = lane >> 4;
  const int i0   = (((int)(blockIdx.x >> 2)) * 4 + wid) * 16;  // wave's 16 rows
  const int oc   = (int)(blockIdx.x & 3);
  const int c0   = oc * 2048;
  const int koff = g * 8;

  // A fragments (this wave's 16 rows), loaded once
  bf16x8 a[4];
  {
    const unsigned short* ap = xb + (size_t)(i0 + l15) * DD + koff;
#pragma unroll
    for (int kk = 0; kk < 4; ++kk)
      a[kk] = *reinterpret_cast<const bf16x8*>(ap + kk * 32);
  }

  const int rowblk = (i0 + g * 4) >> 3;  // lane's 4 rows share one 8-block
  unsigned best[4][KM1];
#pragma unroll
  for (int r = 0; r < 4; ++r)
#pragma unroll
    for (int s = 0; s < KM1; ++s) best[r][s] = 0xFFFFFFFFu;

  for (int t = 0; t < 64; ++t) {
    const int ct = c0 + t * 32;

    bf16x8 b[2][4];
#pragma unroll
    for (int nf = 0; nf < 2; ++nf) {
      const unsigned short* bp = xb + (size_t)(ct + nf * 16 + l15) * DD + koff;
#pragma unroll
      for (int kk = 0; kk < 4; ++kk)
        b[nf][kk] = *reinterpret_cast<const bf16x8*>(bp + kk * 32);
    }

    f32x4 acc[2];
#pragma unroll
    for (int nf = 0; nf < 2; ++nf) acc[nf] = (f32x4){0.f, 0.f, 0.f, 0.f};
#pragma unroll
    for (int nf = 0; nf < 2; ++nf)
#pragma unroll
      for (int kk = 0; kk < 4; ++kk)
        acc[nf] = __builtin_amdgcn_mfma_f32_16x16x32_bf16(a[kk], b[nf][kk], acc[nf], 0, 0, 0);

    // epilogue: C/D layout col = l15, row = g*4 + reg  [m89-verified]
#pragma unroll
    for (int nf = 0; nf < 2; ++nf) {
      const int col  = ct + nf * 16 + l15;
      const bool nblk = ((col >> 3) != rowblk);
#pragma unroll
      for (int r = 0; r < 4; ++r) {
        const int row = i0 + g * 4 + r;
        float dot = acc[nf][r];
        float d2m = fmaxf(fmaf(-2.f, dot, 2.f), 0.25f);   // clamped dist^2
        bool vb  = nblk && (d2m < 1.96f);                 // block mask + dist<1.4
        float lgd = __log2f(d2m);
        float om  = fmaf(-0.25f, d2m, 1.f);
        float lgo = __log2f(om);
        float lgs = fmaf(63.f, lgd, 63.f) + 62.5f * lgo;  // log2((2*d2m)^63 * om^62.5)
        float inw = __builtin_amdgcn_exp2f(lgs);          // 1/w in [1.9e-21, 1.2e19]
        float ks   = vb ? inw * (-0.69314718f) : 0.f;
        float bias = vb ? inw * 22.180710f : __builtin_inff();
        unsigned h = mix32((unsigned)((row << 13) | col) + 0x9E3779B9u);
#pragma unroll
        for (int sm = 0; sm < KM1; ++sm) {
          h = h * 1664525u + 1013904223u;
          float lg  = __log2f((float)(h | 1u));           // [0,32)
          float key = fmaf(lg, ks, bias);                 // E/w >= 0 (inf if masked)
          unsigned pk = (__float_as_uint(key) & 0xFFFFE000u) | (unsigned)col;
          best[r][sm] = best[r][sm] < pk ? best[r][sm] : pk;
        }
      }
    }
  }

  // one cross-lane reduce at the end (over l15 within the same g-group)
#pragma unroll
  for (int r = 0; r < 4; ++r)
#pragma unroll
    for (int s = 0; s < KM1; ++s) {
      unsigned v = best[r][s];
#pragma unroll
      for (int off = 1; off < 16; off <<= 1) {
        unsigned o = (unsigned)__shfl_xor((int)v, off);
        v = v < o ? v : o;
      }
      best[r][s] = v;
    }
  if (l15 == 0) {
#pragma unroll
    for (int r = 0; r < 4; ++r)
#pragma unroll
      for (int s = 0; s < KM1; ++s)
        partial[(size_t)oc * NKEY + (i0 + g * 4 + r) * KM1 + s] = best[r][s];
  }
}

// Min over the 4 quarters; decode winner col; uniform fallback. Writes the
// final index in place over the q=0 slice (each thread owns its slot).
__global__ __launch_bounds__(256) void combine(unsigned* __restrict__ partial) {
  const int idx = blockIdx.x * 256 + threadIdx.x;  // NKEY threads exactly
  unsigned bk = 0xFFFFFFFFu;
#pragma unroll
  for (int q = 0; q < QOC; ++q) {
    unsigned v = partial[(size_t)q * NKEY + idx];
    bk = bk < v ? bk : v;
  }
  unsigned col;
  if (bk >= 0x7F800000u) {  // all masked -> uniform fallback (probs = 1/n)
    col = mix32((unsigned)idx * 0x68bc21ebu + 77u) & (NN - 1);
  } else {
    col = bk & 0x1FFFu;
  }
  partial[idx] = col;
}

// All five output chunks, float4-vectorized.
__global__ __launch_bounds__(256) void write_outputs(const float* __restrict__ x,
                                                     const unsigned* __restrict__ nidx,
                                                     float4* __restrict__ out4) {
  const int qq = blockIdx.x * 256 + threadIdx.x;
  if (qq >= TOTAL / 4) return;
  const int e = qq * 4;
  float4 v;
  if (e < O0_END) {
    v.x = (float)((e    ) / KM1);
    v.y = (float)((e + 1) / KM1);
    v.z = (float)((e + 2) / KM1);
    v.w = (float)((e + 3) / KM1);                        // a_idx
  } else if (e < O1_END) {
    int t = e - O0_END; int sidx = t >> 7; int d = t & 127;
    v = *reinterpret_cast<const float4*>(x + (size_t)(sidx / KM1) * DD + d);   // x[a_idx]
  } else if (e < O2_END) {
    int t = e - O1_END; int sidx = t >> 7; int d = t & 127;
    int i = sidx / KM1; int j = sidx - i * KM1; int m = i & 7;
    int p = (i >> 3) * 8 + j + (j >= m ? 1 : 0);         // block members, skip self
    v = *reinterpret_cast<const float4*>(x + (size_t)p * DD + d);              // x[p_idx]
  } else if (e < O3_END) {
    int t = e - O2_END; int sidx = t >> 7; int d = t & 127;
    int nix = (int)nidx[sidx];
    v = *reinterpret_cast<const float4*>(x + (size_t)nix * DD + d);            // x[n_idx]
  } else {
    v = *reinterpret_cast<const float4*>(x + (e - O3_END));                    // x
  }
  out4[qq] = v;
}

extern "C" void kernel_launch(void* const* d_in, const int* in_sizes, int n_in,
                              void* d_out, int out_size, void* d_ws, size_t ws_size,
                              hipStream_t stream) {
  const float* x = (const float*)d_in[0];
  float* out = (float*)d_out;

  unsigned* partial = (unsigned*)d_ws;                                  // 4*57344 u32
  unsigned short* xb = (unsigned short*)((char*)d_ws + QOC * NKEY * 4); // 2 MB bf16

  hipLaunchKernelGGL(to_bf16, dim3(NN * DD / 4 / 256), dim3(256), 0, stream,
                     (const float4*)x, (ushort4*)xb);
  hipLaunchKernelGGL(sample_mfma, dim3(512), dim3(TPB), 0, stream, xb, partial);
  hipLaunchKernelGGL(combine, dim3(NKEY / 256), dim3(256), 0, stream, partial);
  hipLaunchKernelGGL(write_outputs, dim3(TOTAL / 4 / 256), dim3(256), 0, stream,
                     x, partial, (float4*)out);
}